// Round 2
// baseline (454.666 us; speedup 1.0000x reference)
//
#include <hip/hip_runtime.h>
#include <hip/hip_bf16.h>

typedef unsigned long long u64;

#define BS 4
#define N 4096
#define NW 64              // N/64 bit-words per row
#define RD 64              // scan prefetch ring depth
#define MASK_ROWS (N + RD) // pad so scan prefetch addresses stay in bounds
#define SCORE_THR 0.1f
#define IOU_THR 0.3f
#define MAX_COORD 4096.0f

// ---------------------------------------------------------------------------
// K1: per-image bitonic sort of packed (desc-score, asc-idx) keys in LDS.
// Barrier elision: phases with j<=32 stay within one wave's 64-element
// groups (thread t handles t = tid + 1024*s; wave w owns groups {w, w+16,
// w+32, w+48}), so no __syncthreads needed between consecutive j<=32 phases.
// ---------------------------------------------------------------------------
__global__ __launch_bounds__(1024) void k_sort(const float* __restrict__ preds,
                                               float4* __restrict__ sbox,
                                               int* __restrict__ sidx,
                                               u64* __restrict__ svalidW) {
    __shared__ u64 keys[N];
    const int b = blockIdx.x;
    const float* P = preds + (size_t)b * N * 6;

    for (int p = threadIdx.x; p < N; p += 1024) {
        float s = P[p * 6 + 4];
        bool valid = (s >= SCORE_THR);
        float kf = valid ? s : -INFINITY;
        unsigned u = __float_as_uint(kf);
        u = (u & 0x80000000u) ? ~u : (u | 0x80000000u);  // monotone asc map
        unsigned desc = ~u;                              // invert -> descending
        keys[p] = ((u64)desc << 32) | (unsigned)p;
    }

    bool prev_cross = true;  // fill loop writes cross-checked groups? own-group, but be safe
    for (int k = 2; k <= N; k <<= 1) {
        for (int j = k >> 1; j > 0; j >>= 1) {
            bool cross = (j >= 64);
            if (cross || prev_cross) __syncthreads();
            for (int t = threadIdx.x; t < N; t += 1024) {
                int ixj = t ^ j;
                if (ixj > t) {
                    bool up = ((t & k) == 0);
                    u64 a = keys[t], c = keys[ixj];
                    if ((a > c) == up) { keys[t] = c; keys[ixj] = a; }
                }
            }
            prev_cross = cross;
        }
    }
    __syncthreads();

    for (int p = threadIdx.x; p < N; p += 1024) {
        int idx = (int)(keys[p] & 0xFFFFFFFFull);
        const float* R = P + (size_t)idx * 6;
        float x1 = R[0], y1 = R[1], x2 = R[2], y2 = R[3], sc = R[4], cl = R[5];
        float off = cl * MAX_COORD;
        sbox[b * N + p] = make_float4(x1 + off, y1 + off, x2 + off, y2 + off);
        sidx[b * N + p] = idx;
        bool valid = (sc >= SCORE_THR);
        u64 m = __ballot(valid);
        if ((threadIdx.x & 63) == 0) svalidW[b * NW + (p >> 6)] = m;
    }
}

// ---------------------------------------------------------------------------
// K2: suppression bit-matrix via ballot. lane = column j = wc*64+lane; row is
// wave-uniform (row box scalarizes). Column boxes register-cached once per
// wave. Only upper-triangle words (wc >= row>>6) are computed AND stored —
// the scan never reads the rest.
// grid (wc: 64, rowchunk: 4, b: 4), block 256 = 4 waves x 256 rows each.
// ---------------------------------------------------------------------------
__global__ __launch_bounds__(256) void k_mask(const float4* __restrict__ sbox,
                                              u64* __restrict__ mask) {
    const int b = blockIdx.z;
    const int wc = blockIdx.x;
    const int wave = threadIdx.x >> 6;
    const int lane = threadIdx.x & 63;
    const int j = wc * 64 + lane;
    const int rbase = blockIdx.y * 1024 + wave * 256;
    const int rend = min(rbase + 256, wc * 64 + 64);  // rows with row>>6 <= wc
    if (rend <= rbase) return;

    const float4* S = sbox + b * N;
    const float4 cb = S[j];
    const float carea = (cb.z - cb.x) * (cb.w - cb.y);
    u64* M = mask + (size_t)b * MASK_ROWS * NW;

    for (int row = rbase; row < rend; ++row) {
        float4 rb = S[row];  // wave-uniform -> scalar load
        float rarea = (rb.z - rb.x) * (rb.w - rb.y);
        float ix1 = fmaxf(rb.x, cb.x), iy1 = fmaxf(rb.y, cb.y);
        float ix2 = fminf(rb.z, cb.z), iy2 = fminf(rb.w, cb.w);
        float iw = fmaxf(ix2 - ix1, 0.0f), ih = fmaxf(iy2 - iy1, 0.0f);
        float inter = iw * ih;
        float iou = inter / (rarea + carea - inter + 1e-9f);  // IEEE, same as ref
        bool sup = (iou > IOU_THR) && (j > row);
        u64 word = __ballot(sup);
        if (lane == 0) M[(size_t)row * NW + wc] = word;
    }
}

// ---------------------------------------------------------------------------
// K3: serial greedy scan, one wave per image. Lane l holds removed word l.
// Scalar `cur` mirrors removed[word wi]; refreshed once per 64 rows, updated
// incrementally on keeps -> skip iterations are pure-scalar (~5 cyc).
// 64-deep predicated prefetch ring (only lanes >= wi load -> upper triangle).
// ---------------------------------------------------------------------------
__device__ __forceinline__ u64 readlane64(u64 v, int l) {
    unsigned lo = (unsigned)__builtin_amdgcn_readlane((int)(unsigned)v, l);
    unsigned hi = (unsigned)__builtin_amdgcn_readlane((int)(unsigned)(v >> 32), l);
    return ((u64)hi << 32) | (u64)lo;
}

__global__ __launch_bounds__(64, 1) void k_scan(const u64* __restrict__ mask,
                                                const u64* __restrict__ svalidW,
                                                u64* __restrict__ keptW) {
    const int b = blockIdx.x;
    const int lane = threadIdx.x;
    const u64* M = mask + (size_t)b * MASK_ROWS * NW;

    u64 removed = ~svalidW[b * NW + lane];
    u64 keptword = 0;

    u64 pf[RD];
#pragma unroll
    for (int k = 0; k < RD; ++k) pf[k] = M[(size_t)k * NW + lane];  // rows 0..63: wi=0, all lanes

    for (int ib = 0; ib < N / RD; ++ib) {
        u64 cur = readlane64(removed, ib);  // removed word for this 64-row block
        u64 kw = 0;
#pragma unroll
        for (int u = 0; u < RD; ++u) {
            const int i = ib * RD + u;
            u64 row = pf[u];
            // prefetch row i+RD; its word index is ib+1 -> only lanes >= ib+1 matter
            const int pwi = (i + RD) >> 6;
            u64 nv = 0;
            if (lane >= pwi) nv = M[(size_t)(i + RD) * NW + lane];
            pf[u] = nv;

            if (!((cur >> u) & 1ull)) {      // keep row i (u is a literal: s_bitcmp)
                removed |= row;               // off the scalar critical path
                cur |= readlane64(row, ib);   // in-word suppressions
                kw |= (1ull << u);
            }
        }
        if (lane == ib) keptword = kw;
    }
    keptW[b * NW + lane] = keptword;
}

// ---------------------------------------------------------------------------
// K4: scatter output. Each sorted position maps to a unique original row.
// ---------------------------------------------------------------------------
__global__ __launch_bounds__(256) void k_out(const float* __restrict__ preds,
                                             const int* __restrict__ sidx,
                                             const u64* __restrict__ keptW,
                                             float* __restrict__ out) {
    const int b = blockIdx.y;
    const int p = blockIdx.x * 256 + threadIdx.x;
    const int idx = sidx[b * N + p];
    const bool keep = (keptW[b * NW + (p >> 6)] >> (p & 63)) & 1ull;
    const float* R = preds + ((size_t)b * N + idx) * 6;
    float* O = out + ((size_t)b * N + idx) * 6;
#pragma unroll
    for (int q = 0; q < 6; ++q) O[q] = keep ? R[q] : 0.0f;
}

extern "C" void kernel_launch(void* const* d_in, const int* in_sizes, int n_in,
                              void* d_out, int out_size, void* d_ws, size_t ws_size,
                              hipStream_t stream) {
    const float* preds = (const float*)d_in[0];
    float* out = (float*)d_out;

    // ws layout: [mask][sbox][sidx][svalidW][keptW]
    u64* mask = (u64*)d_ws;
    char* p = (char*)d_ws + (size_t)BS * MASK_ROWS * NW * sizeof(u64);
    float4* sbox = (float4*)p;      p += (size_t)BS * N * sizeof(float4);
    int* sidx = (int*)p;            p += (size_t)BS * N * sizeof(int);
    u64* svalidW = (u64*)p;         p += (size_t)BS * NW * sizeof(u64);
    u64* keptW = (u64*)p;

    k_sort<<<BS, 1024, 0, stream>>>(preds, sbox, sidx, svalidW);
    k_mask<<<dim3(NW, 4, BS), 256, 0, stream>>>(sbox, mask);
    k_scan<<<BS, 64, 0, stream>>>(mask, svalidW, keptW);
    k_out<<<dim3(N / 256, BS), 256, 0, stream>>>(preds, sidx, keptW, out);
}

// Round 3
// 397.114 us; speedup vs baseline: 1.1449x; 1.1449x over previous
//
#include <hip/hip_runtime.h>
#include <hip/hip_bf16.h>

typedef unsigned long long u64;

#define BS 4
#define N 4096
#define NW 64              // N/64 bit-words per row
#define SCORE_THR 0.1f
#define IOU_THR 0.3f
#define MAX_COORD 4096.0f

__device__ __forceinline__ u64 readlane64(u64 v, int l) {
    unsigned lo = (unsigned)__builtin_amdgcn_readlane((int)(unsigned)v, l);
    unsigned hi = (unsigned)__builtin_amdgcn_readlane((int)(unsigned)(v >> 32), l);
    return ((u64)hi << 32) | (u64)lo;
}
__device__ __forceinline__ u64 readfirstlane64(u64 v) {
    unsigned lo = (unsigned)__builtin_amdgcn_readfirstlane((int)(unsigned)v);
    unsigned hi = (unsigned)__builtin_amdgcn_readfirstlane((int)(unsigned)(v >> 32));
    return ((u64)hi << 32) | (u64)lo;
}

// ---------------------------------------------------------------------------
// K1: per-image bitonic sort of packed (desc-score, asc-idx) keys in LDS.
// (unchanged from round 2 — proven correct; rewrite pending attribution)
// ---------------------------------------------------------------------------
__global__ __launch_bounds__(1024) void k_sort(const float* __restrict__ preds,
                                               float4* __restrict__ sbox,
                                               int* __restrict__ sidx,
                                               u64* __restrict__ svalidW) {
    __shared__ u64 keys[N];
    const int b = blockIdx.x;
    const float* P = preds + (size_t)b * N * 6;

    for (int p = threadIdx.x; p < N; p += 1024) {
        float s = P[p * 6 + 4];
        bool valid = (s >= SCORE_THR);
        float kf = valid ? s : -INFINITY;
        unsigned u = __float_as_uint(kf);
        u = (u & 0x80000000u) ? ~u : (u | 0x80000000u);  // monotone asc map
        unsigned desc = ~u;                              // invert -> descending
        keys[p] = ((u64)desc << 32) | (unsigned)p;
    }

    bool prev_cross = true;
    for (int k = 2; k <= N; k <<= 1) {
        for (int j = k >> 1; j > 0; j >>= 1) {
            bool cross = (j >= 64);
            if (cross || prev_cross) __syncthreads();
            for (int t = threadIdx.x; t < N; t += 1024) {
                int ixj = t ^ j;
                if (ixj > t) {
                    bool up = ((t & k) == 0);
                    u64 a = keys[t], c = keys[ixj];
                    if ((a > c) == up) { keys[t] = c; keys[ixj] = a; }
                }
            }
            prev_cross = cross;
        }
    }
    __syncthreads();

    for (int p = threadIdx.x; p < N; p += 1024) {
        int idx = (int)(keys[p] & 0xFFFFFFFFull);
        const float* R = P + (size_t)idx * 6;
        float x1 = R[0], y1 = R[1], x2 = R[2], y2 = R[3], sc = R[4], cl = R[5];
        float off = cl * MAX_COORD;
        sbox[b * N + p] = make_float4(x1 + off, y1 + off, x2 + off, y2 + off);
        sidx[b * N + p] = idx;
        bool valid = (sc >= SCORE_THR);
        u64 m = __ballot(valid);
        if ((threadIdx.x & 63) == 0) svalidW[b * NW + (p >> 6)] = m;
    }
}

// ---------------------------------------------------------------------------
// K2: suppression bit-matrix via ballot, stored TRANSPOSED:
// MT[img][wc*N + row] = 64-bit word of (iou(row, wc*64+lane)>thr && col>row).
// Column wc is contiguous over rows -> DMA-friendly for the scan.
// Only upper-triangle words (wc >= row>>6) computed/stored.
// ---------------------------------------------------------------------------
__global__ __launch_bounds__(256) void k_mask(const float4* __restrict__ sbox,
                                              u64* __restrict__ maskT) {
    const int b = blockIdx.z;
    const int wc = blockIdx.x;
    const int wave = threadIdx.x >> 6;
    const int lane = threadIdx.x & 63;
    const int j = wc * 64 + lane;
    const int rbase = blockIdx.y * 1024 + wave * 256;
    const int rend = min(rbase + 256, wc * 64 + 64);  // rows with row>>6 <= wc
    if (rend <= rbase) return;

    const float4* S = sbox + b * N;
    const float4 cb = S[j];
    const float carea = (cb.z - cb.x) * (cb.w - cb.y);
    u64* MT = maskT + (size_t)b * N * NW;

    for (int row = rbase; row < rend; ++row) {
        float4 rb = S[row];  // wave-uniform -> scalar load
        float rarea = (rb.z - rb.x) * (rb.w - rb.y);
        float ix1 = fmaxf(rb.x, cb.x), iy1 = fmaxf(rb.y, cb.y);
        float ix2 = fminf(rb.z, cb.z), iy2 = fminf(rb.w, cb.w);
        float iw = fmaxf(ix2 - ix1, 0.0f), ih = fmaxf(iy2 - iy1, 0.0f);
        float inter = iw * ih;
        float iou = inter / (rarea + carea - inter + 1e-9f);  // IEEE, same as ref
        bool sup = (iou > IOU_THR) && (j > row);
        u64 word = __ballot(sup);
        if (lane == 0) MT[(size_t)wc * N + row] = word;
    }
}

// ---------------------------------------------------------------------------
// K3: column-block scan. One wave per image. Per 64-row block b:
//   apply:   t_l = OR over u<b of (kept(64u+lane) ? MT[b][64u+lane] : 0)
//            (LDS reads from DMA'd column, VALU cndmask/or — all parallel)
//   reduce:  s = OR of t_l across lanes (shfl_xor), cur = ~valid_b | s
//   resolve: 64 serial scalar steps over the diagonal block (readlane on keep)
// Column b+1 DMA'd into the other LDS buffer during block b (global_load_lds,
// zero VGPR cost); s_waitcnt vmcnt(0) at block entry = wait for exactly it.
// Kept bits held bit-transposed: kb[lane] bit u = kept(row 64u+lane).
// ---------------------------------------------------------------------------
__global__ __launch_bounds__(64, 1) void k_scan(const u64* __restrict__ maskT,
                                                const u64* __restrict__ svalidW,
                                                u64* __restrict__ keptW) {
    __shared__ u64 colbuf[2][N];   // 2 x 32 KB
    const int img = blockIdx.x;
    const int lane = threadIdx.x;
    const u64* M = maskT + (size_t)img * N * NW;

    u64 vvalid = svalidW[img * NW + lane];  // lane l: valid word for rows 64l..
    u64 kb = 0;                             // transposed kept bits

    // DMA column 0 into buffer 0 (32 instrs x 1 KiB, zero VGPR)
    {
        const char* g = (const char*)M + lane * 16;
        for (int c = 0; c < 32; ++c)
            __builtin_amdgcn_global_load_lds((const unsigned int*)(g + c * 1024),
                                             (unsigned int*)&colbuf[0][c * 128], 16, 0, 0);
    }

    for (int b = 0; b < 64; ++b) {
        asm volatile("s_waitcnt vmcnt(0)" ::: "memory");  // column b resident
        if (b + 1 < 64) {  // prefetch column b+1 into other buffer
            const char* g = (const char*)(M + (size_t)(b + 1) * N) + lane * 16;
            for (int c = 0; c < 32; ++c)
                __builtin_amdgcn_global_load_lds((const unsigned int*)(g + c * 1024),
                                                 (unsigned int*)&colbuf[(b + 1) & 1][c * 128], 16, 0, 0);
        }
        const u64* cb = &colbuf[b & 1][lane];

        u64 diag = cb[(size_t)b * 64];     // row 64b+lane, word b (issued early)
        u64 valid_b = readlane64(vvalid, b);
        u64 t = 0;
        for (int u = 0; u < b; ++u)
            t |= (((kb >> u) & 1ull) ? cb[(size_t)u * 64] : 0ull);

        // OR-reduce t across 64 lanes
        t |= __shfl_xor(t, 32, 64);
        t |= __shfl_xor(t, 16, 64);
        t |= __shfl_xor(t, 8, 64);
        t |= __shfl_xor(t, 4, 64);
        t |= __shfl_xor(t, 2, 64);
        t |= __shfl_xor(t, 1, 64);

        u64 cur = (~valid_b) | readfirstlane64(t);
        u64 kw = 0;
#pragma unroll
        for (int v = 0; v < 64; ++v) {
            if (!((cur >> v) & 1ull)) {        // scalar bit test, literal v
                cur |= readlane64(diag, v);    // in-block suppression
                kw |= (1ull << v);
            }
        }
        kb |= ((kw >> lane) & 1ull) << b;      // scatter kept bits (transposed)
    }
    keptW[img * NW + lane] = kb;
}

// ---------------------------------------------------------------------------
// K4: scatter output. kept bit for sorted pos p is keptW[p&63] bit (p>>6).
// ---------------------------------------------------------------------------
__global__ __launch_bounds__(256) void k_out(const float* __restrict__ preds,
                                             const int* __restrict__ sidx,
                                             const u64* __restrict__ keptW,
                                             float* __restrict__ out) {
    const int b = blockIdx.y;
    const int p = blockIdx.x * 256 + threadIdx.x;
    const int idx = sidx[b * N + p];
    const bool keep = (keptW[b * NW + (p & 63)] >> (p >> 6)) & 1ull;
    const float* R = preds + ((size_t)b * N + idx) * 6;
    float* O = out + ((size_t)b * N + idx) * 6;
#pragma unroll
    for (int q = 0; q < 6; ++q) O[q] = keep ? R[q] : 0.0f;
}

extern "C" void kernel_launch(void* const* d_in, const int* in_sizes, int n_in,
                              void* d_out, int out_size, void* d_ws, size_t ws_size,
                              hipStream_t stream) {
    const float* preds = (const float*)d_in[0];
    float* out = (float*)d_out;

    // ws layout: [maskT: BS*N*NW u64][sbox][sidx][svalidW][keptW]
    u64* maskT = (u64*)d_ws;
    char* p = (char*)d_ws + (size_t)BS * N * NW * sizeof(u64);
    float4* sbox = (float4*)p;      p += (size_t)BS * N * sizeof(float4);
    int* sidx = (int*)p;            p += (size_t)BS * N * sizeof(int);
    u64* svalidW = (u64*)p;         p += (size_t)BS * NW * sizeof(u64);
    u64* keptW = (u64*)p;

    k_sort<<<BS, 1024, 0, stream>>>(preds, sbox, sidx, svalidW);
    k_mask<<<dim3(NW, 4, BS), 256, 0, stream>>>(sbox, maskT);
    k_scan<<<BS, 64, 0, stream>>>(maskT, svalidW, keptW);
    k_out<<<dim3(N / 256, BS), 256, 0, stream>>>(preds, sidx, keptW, out);
}

// Round 4
// 395.239 us; speedup vs baseline: 1.1504x; 1.0047x over previous
//
#include <hip/hip_runtime.h>
#include <hip/hip_bf16.h>

typedef unsigned long long u64;

#define BS 4
#define N 4096
#define NW 64              // N/64 bit-words per row
#define SCORE_THR 0.1f
#define IOU_THR 0.3f
#define MAX_COORD 4096.0f

__device__ __forceinline__ u64 readlane64(u64 v, int l) {
    unsigned lo = (unsigned)__builtin_amdgcn_readlane((int)(unsigned)v, l);
    unsigned hi = (unsigned)__builtin_amdgcn_readlane((int)(unsigned)(v >> 32), l);
    return ((u64)hi << 32) | (u64)lo;
}
__device__ __forceinline__ u64 readfirstlane64(u64 v) {
    unsigned lo = (unsigned)__builtin_amdgcn_readfirstlane((int)(unsigned)v);
    unsigned hi = (unsigned)__builtin_amdgcn_readfirstlane((int)(unsigned)(v >> 32));
    return ((u64)hi << 32) | (u64)lo;
}
__device__ __forceinline__ u64 shfl_xor64(u64 v, int lx) {
    int lo = __shfl_xor((int)(unsigned)v, lx, 64);
    int hi = __shfl_xor((int)(unsigned)(v >> 32), lx, 64);
    return ((u64)(unsigned)hi << 32) | (u64)(unsigned)lo;
}

#define CAS(a, b, asc) { if (((a) > (b)) == (asc)) { u64 _t = (a); (a) = (b); (b) = _t; } }

// ---------------------------------------------------------------------------
// K1: register-blocked bitonic sort. 1024 threads x 4 elements (e = 4t+r).
// j=1,2: intra-thread; j=4..128: shfl_xor (lane ^= j>>2); j>=256: LDS.
// Key = (descending-score monotone u32 << 32) | idx  -> ascending u64 sort
// reproduces jnp.argsort(-score) stable order exactly.
// ---------------------------------------------------------------------------
__global__ __launch_bounds__(1024) void k_sort(const float* __restrict__ preds,
                                               float4* __restrict__ sbox,
                                               int* __restrict__ sidx,
                                               u64* __restrict__ svalidW) {
    __shared__ u64 keys[N];
    __shared__ unsigned valw[128];
    const int b = blockIdx.x;
    const int t = threadIdx.x;
    const float* P = preds + (size_t)b * N * 6;

    if (t < 128) valw[t] = 0;   // sort barriers below order this vs the atomics

    u64 V[4];
#pragma unroll
    for (int r = 0; r < 4; ++r) {
        int e = 4 * t + r;
        float s = P[e * 6 + 4];
        bool valid = (s >= SCORE_THR);
        float kf = valid ? s : -INFINITY;
        unsigned u = __float_as_uint(kf);
        u = (u & 0x80000000u) ? ~u : (u | 0x80000000u);  // monotone asc map
        unsigned desc = ~u;                              // descending
        V[r] = ((u64)desc << 32) | (unsigned)e;
    }

    // k = 2
    CAS(V[0], V[1], true);
    CAS(V[2], V[3], false);

    for (int k = 4; k <= N; k <<= 1) {
        const bool asc = (((4 * t) & k) == 0);  // uniform for this thread's 4 elems

        if ((k >> 1) >= 256) {
            // LDS phases: j = k/2 .. 256
#pragma unroll
            for (int r = 0; r < 4; ++r) keys[4 * t + r] = V[r];
            __syncthreads();
            for (int j = k >> 1; j >= 256; j >>= 1) {
                const bool lower = (((4 * t) & j) == 0);
                const bool takemin = (lower == asc);
#pragma unroll
                for (int r = 0; r < 4; ++r) {
                    u64 pv = keys[(4 * t + r) ^ j];
                    u64 lo = V[r] < pv ? V[r] : pv;
                    u64 hi = V[r] < pv ? pv : V[r];
                    V[r] = takemin ? lo : hi;
                }
                __syncthreads();
#pragma unroll
                for (int r = 0; r < 4; ++r) keys[4 * t + r] = V[r];
                __syncthreads();
            }
        }
        // shfl phases: j = min(k/2,128) .. 4
        for (int j = ((k >> 1) > 128 ? 128 : (k >> 1)); j >= 4; j >>= 1) {
            const bool lower = (((4 * t) & j) == 0);
            const bool takemin = (lower == asc);
            const int lx = j >> 2;
#pragma unroll
            for (int r = 0; r < 4; ++r) {
                u64 pv = shfl_xor64(V[r], lx);
                u64 lo = V[r] < pv ? V[r] : pv;
                u64 hi = V[r] < pv ? pv : V[r];
                V[r] = takemin ? lo : hi;
            }
        }
        // j = 2: pairs (0,2),(1,3); j = 1: pairs (0,1),(2,3)
        CAS(V[0], V[2], asc); CAS(V[1], V[3], asc);
        CAS(V[0], V[1], asc); CAS(V[2], V[3], asc);
    }

    // outputs
#pragma unroll
    for (int r = 0; r < 4; ++r) {
        int e = 4 * t + r;
        int idx = (int)(V[r] & 0xFFFFFFFFull);
        const float* R = P + (size_t)idx * 6;
        float x1 = R[0], y1 = R[1], x2 = R[2], y2 = R[3], sc = R[4], cl = R[5];
        float off = cl * MAX_COORD;
        sbox[b * N + e] = make_float4(x1 + off, y1 + off, x2 + off, y2 + off);
        sidx[b * N + e] = idx;
        if (sc >= SCORE_THR) atomicOr(&valw[e >> 5], 1u << (e & 31));
    }
    __syncthreads();
    if (t < 64) svalidW[b * NW + t] = (u64)valw[2 * t] | ((u64)valw[2 * t + 1] << 32);
}

// ---------------------------------------------------------------------------
// K2: suppression bit-matrix via ballot, ROW-MAJOR: M[row*64+wc] bit l =
// (iou(row, wc*64+l)>thr && col>row). Upper-triangle (wc >= row>>6) only.
// ---------------------------------------------------------------------------
__global__ __launch_bounds__(256) void k_mask(const float4* __restrict__ sbox,
                                              u64* __restrict__ mask) {
    const int b = blockIdx.z;
    const int wc = blockIdx.x;
    const int wave = threadIdx.x >> 6;
    const int lane = threadIdx.x & 63;
    const int j = wc * 64 + lane;
    const int rbase = blockIdx.y * 1024 + wave * 256;
    const int rend = min(rbase + 256, wc * 64 + 64);
    if (rend <= rbase) return;

    const float4* S = sbox + b * N;
    const float4 cb = S[j];
    const float carea = (cb.z - cb.x) * (cb.w - cb.y);
    u64* M = mask + (size_t)b * N * NW;

    for (int row = rbase; row < rend; ++row) {
        float4 rb = S[row];  // wave-uniform -> scalar load
        float rarea = (rb.z - rb.x) * (rb.w - rb.y);
        float ix1 = fmaxf(rb.x, cb.x), iy1 = fmaxf(rb.y, cb.y);
        float ix2 = fminf(rb.z, cb.z), iy2 = fminf(rb.w, cb.w);
        float iw = fmaxf(ix2 - ix1, 0.0f), ih = fmaxf(iy2 - iy1, 0.0f);
        float inter = iw * ih;
        float iou = inter / (rarea + carea - inter + 1e-9f);  // IEEE, same as ref
        bool sup = (iou > IOU_THR) && (j > row);
        u64 word = __ballot(sup);
        if (lane == 0) M[(size_t)row * NW + wc] = word;
    }
}

// ---------------------------------------------------------------------------
// K3: 4-wave scan per image. 32KB row-chunks stream through a 3-deep LDS ring
// (global_load_lds, raw s_barrier + fixed vmcnt(8) so prefetch stays in
// flight). Wave w>0 applies kept rows (v mod 3 == w-1) into its private
// distributed `removed` (lane=word); block-entry word = OR of 4 wave parts.
// Wave 0 resolves the 64-row diagonal serially in scalar regs.
// ---------------------------------------------------------------------------
__global__ __launch_bounds__(256, 1) void k_scan(const u64* __restrict__ mask,
                                                 const u64* __restrict__ svalidW,
                                                 u64* __restrict__ keptW) {
    __shared__ u64 chunk[3][4096];   // 3 x 32 KB
    __shared__ u64 part[4];
    __shared__ u64 kwLDS;
    __shared__ u64 keptLDS[64];
    const int img = blockIdx.x;
    const int w = threadIdx.x >> 6;
    const int lane = threadIdx.x & 63;
    const u64* Mi = mask + (size_t)img * N * NW;

    u64 removed = 0;
    u64 vvalid = 0;
    if (w == 0) vvalid = svalidW[img * NW + lane];

    // prime: chunks 0 and 1 (each: 8 instr/wave, wave w covers bytes (c*4+w)*1024)
#pragma unroll
    for (int c = 0; c < 8; ++c)
        __builtin_amdgcn_global_load_lds(
            (const unsigned*)((const char*)Mi + (size_t)(c * 4 + w) * 1024 + lane * 16),
            (unsigned*)((char*)&chunk[0][0] + (c * 4 + w) * 1024), 16, 0, 0);
    asm volatile("" ::: "memory");
#pragma unroll
    for (int c = 0; c < 8; ++c)
        __builtin_amdgcn_global_load_lds(
            (const unsigned*)((const char*)Mi + 32768 + (size_t)(c * 4 + w) * 1024 + lane * 16),
            (unsigned*)((char*)&chunk[1][0] + (c * 4 + w) * 1024), 16, 0, 0);
    asm volatile("" ::: "memory");

    for (int bb = 0; bb < 64; ++bb) {
        const u64* cbuf = &chunk[bb % 3][0];
        // s1: contribute this wave's removed-word for block bb
        u64 rd = readlane64(removed, bb);
        if (lane == 0) part[w] = rd;
        // s2: chunk bb resident for everyone (+ LDS writes visible), keep
        // chunk bb+1 (8 loads/wave) in flight. b==0 drains all (prime safety).
        if (bb == 0) asm volatile("s_waitcnt vmcnt(0) lgkmcnt(0)" ::: "memory");
        else         asm volatile("s_waitcnt vmcnt(8) lgkmcnt(0)" ::: "memory");
        __builtin_amdgcn_s_barrier();
        asm volatile("" ::: "memory");
        // s3: issue DMA for chunk bb+2 into ring slot (bb+2)%3 (clamped 63)
        {
            int bs = (bb + 2 > 63) ? 63 : (bb + 2);
            const char* gsc = (const char*)Mi + (size_t)bs * 32768;
            char* dbase = (char*)&chunk[(bb + 2) % 3][0];
#pragma unroll
            for (int c = 0; c < 8; ++c)
                __builtin_amdgcn_global_load_lds(
                    (const unsigned*)(gsc + (size_t)(c * 4 + w) * 1024 + lane * 16),
                    (unsigned*)(dbase + (c * 4 + w) * 1024), 16, 0, 0);
        }
        asm volatile("" ::: "memory");
        // s3b: wave 0 resolves the diagonal block serially
        if (w == 0) {
            u64 diag = cbuf[(size_t)lane * 64 + bb];  // row 64bb+lane, word bb
            u64 ps = part[0] | part[1] | part[2] | part[3];
            u64 cur = ~readlane64(vvalid, bb) | readfirstlane64(ps);
            u64 kw = 0;
#pragma unroll
            for (int v = 0; v < 64; ++v) {
                if (!((cur >> v) & 1ull)) {        // scalar bit test, literal v
                    cur |= readlane64(diag, v);    // in-block suppression
                    kw |= (1ull << v);
                }
            }
            if (lane == 0) { kwLDS = kw; keptLDS[bb] = kw; }
        }
        // s4: broadcast kw (no vmcnt drain -> prefetch stays in flight)
        asm volatile("s_waitcnt lgkmcnt(0)" ::: "memory");
        __builtin_amdgcn_s_barrier();
        asm volatile("" ::: "memory");
        // s5: waves 1..3 apply kept rows into their removed words
        if (w > 0) {
            u64 kws = readfirstlane64(kwLDS);
#pragma unroll
            for (int i = 0; i < 22; ++i) {
                int v = i * 3 + (w - 1);
                if (v < 64 && ((kws >> v) & 1ull))
                    removed |= cbuf[(size_t)v * 64 + lane];
            }
        }
    }
    if (w == 0) keptW[img * NW + lane] = keptLDS[lane];
}

// ---------------------------------------------------------------------------
// K4: scatter output. kept bit for sorted pos p: keptW word p>>6, bit p&63.
// ---------------------------------------------------------------------------
__global__ __launch_bounds__(256) void k_out(const float* __restrict__ preds,
                                             const int* __restrict__ sidx,
                                             const u64* __restrict__ keptW,
                                             float* __restrict__ out) {
    const int b = blockIdx.y;
    const int p = blockIdx.x * 256 + threadIdx.x;
    const int idx = sidx[b * N + p];
    const bool keep = (keptW[b * NW + (p >> 6)] >> (p & 63)) & 1ull;
    const float* R = preds + ((size_t)b * N + idx) * 6;
    float* O = out + ((size_t)b * N + idx) * 6;
#pragma unroll
    for (int q = 0; q < 6; ++q) O[q] = keep ? R[q] : 0.0f;
}

extern "C" void kernel_launch(void* const* d_in, const int* in_sizes, int n_in,
                              void* d_out, int out_size, void* d_ws, size_t ws_size,
                              hipStream_t stream) {
    const float* preds = (const float*)d_in[0];
    float* out = (float*)d_out;

    // ws layout: [mask: BS*N*NW u64][sbox][sidx][svalidW][keptW]
    u64* mask = (u64*)d_ws;
    char* p = (char*)d_ws + (size_t)BS * N * NW * sizeof(u64);
    float4* sbox = (float4*)p;      p += (size_t)BS * N * sizeof(float4);
    int* sidx = (int*)p;            p += (size_t)BS * N * sizeof(int);
    u64* svalidW = (u64*)p;         p += (size_t)BS * NW * sizeof(u64);
    u64* keptW = (u64*)p;

    k_sort<<<BS, 1024, 0, stream>>>(preds, sbox, sidx, svalidW);
    k_mask<<<dim3(NW, 4, BS), 256, 0, stream>>>(sbox, mask);
    k_scan<<<BS, 256, 0, stream>>>(mask, svalidW, keptW);
    k_out<<<dim3(N / 256, BS), 256, 0, stream>>>(preds, sidx, keptW, out);
}

// Round 5
// 335.411 us; speedup vs baseline: 1.3556x; 1.1784x over previous
//
#include <hip/hip_runtime.h>
#include <hip/hip_bf16.h>

typedef unsigned long long u64;

#define BS 4
#define N 4096
#define NW 64              // N/64 bit-words per row
#define SCORE_THR 0.1f
#define IOU_THR 0.3f
#define MAX_COORD 4096.0f

__device__ __forceinline__ u64 readlane64(u64 v, int l) {
    unsigned lo = (unsigned)__builtin_amdgcn_readlane((int)(unsigned)v, l);
    unsigned hi = (unsigned)__builtin_amdgcn_readlane((int)(unsigned)(v >> 32), l);
    return ((u64)hi << 32) | (u64)lo;
}
__device__ __forceinline__ u64 readfirstlane64(u64 v) {
    unsigned lo = (unsigned)__builtin_amdgcn_readfirstlane((int)(unsigned)v);
    unsigned hi = (unsigned)__builtin_amdgcn_readfirstlane((int)(unsigned)(v >> 32));
    return ((u64)hi << 32) | (u64)lo;
}
__device__ __forceinline__ u64 shfl_xor64(u64 v, int lx) {
    int lo = __shfl_xor((int)(unsigned)v, lx, 64);
    int hi = __shfl_xor((int)(unsigned)(v >> 32), lx, 64);
    return ((u64)(unsigned)hi << 32) | (u64)(unsigned)lo;
}

#define CAS(a, b, asc) { if (((a) > (b)) == (asc)) { u64 _t = (a); (a) = (b); (b) = _t; } }

// ---------------------------------------------------------------------------
// K1: register-blocked bitonic sort (unchanged from round 4 — correct).
// ---------------------------------------------------------------------------
__global__ __launch_bounds__(1024) void k_sort(const float* __restrict__ preds,
                                               float4* __restrict__ sbox,
                                               int* __restrict__ sidx,
                                               u64* __restrict__ svalidW) {
    __shared__ u64 keys[N];
    __shared__ unsigned valw[128];
    const int b = blockIdx.x;
    const int t = threadIdx.x;
    const float* P = preds + (size_t)b * N * 6;

    if (t < 128) valw[t] = 0;

    u64 V[4];
#pragma unroll
    for (int r = 0; r < 4; ++r) {
        int e = 4 * t + r;
        float s = P[e * 6 + 4];
        bool valid = (s >= SCORE_THR);
        float kf = valid ? s : -INFINITY;
        unsigned u = __float_as_uint(kf);
        u = (u & 0x80000000u) ? ~u : (u | 0x80000000u);
        unsigned desc = ~u;
        V[r] = ((u64)desc << 32) | (unsigned)e;
    }

    CAS(V[0], V[1], true);
    CAS(V[2], V[3], false);

    for (int k = 4; k <= N; k <<= 1) {
        const bool asc = (((4 * t) & k) == 0);

        if ((k >> 1) >= 256) {
#pragma unroll
            for (int r = 0; r < 4; ++r) keys[4 * t + r] = V[r];
            __syncthreads();
            for (int j = k >> 1; j >= 256; j >>= 1) {
                const bool lower = (((4 * t) & j) == 0);
                const bool takemin = (lower == asc);
#pragma unroll
                for (int r = 0; r < 4; ++r) {
                    u64 pv = keys[(4 * t + r) ^ j];
                    u64 lo = V[r] < pv ? V[r] : pv;
                    u64 hi = V[r] < pv ? pv : V[r];
                    V[r] = takemin ? lo : hi;
                }
                __syncthreads();
#pragma unroll
                for (int r = 0; r < 4; ++r) keys[4 * t + r] = V[r];
                __syncthreads();
            }
        }
        for (int j = ((k >> 1) > 128 ? 128 : (k >> 1)); j >= 4; j >>= 1) {
            const bool lower = (((4 * t) & j) == 0);
            const bool takemin = (lower == asc);
            const int lx = j >> 2;
#pragma unroll
            for (int r = 0; r < 4; ++r) {
                u64 pv = shfl_xor64(V[r], lx);
                u64 lo = V[r] < pv ? V[r] : pv;
                u64 hi = V[r] < pv ? pv : V[r];
                V[r] = takemin ? lo : hi;
            }
        }
        CAS(V[0], V[2], asc); CAS(V[1], V[3], asc);
        CAS(V[0], V[1], asc); CAS(V[2], V[3], asc);
    }

#pragma unroll
    for (int r = 0; r < 4; ++r) {
        int e = 4 * t + r;
        int idx = (int)(V[r] & 0xFFFFFFFFull);
        const float* R = P + (size_t)idx * 6;
        float x1 = R[0], y1 = R[1], x2 = R[2], y2 = R[3], sc = R[4], cl = R[5];
        float off = cl * MAX_COORD;
        sbox[b * N + e] = make_float4(x1 + off, y1 + off, x2 + off, y2 + off);
        sidx[b * N + e] = idx;
        if (sc >= SCORE_THR) atomicOr(&valw[e >> 5], 1u << (e & 31));
    }
    __syncthreads();
    if (t < 64) svalidW[b * NW + t] = (u64)valw[2 * t] | ((u64)valw[2 * t + 1] << 32);
}

// ---------------------------------------------------------------------------
// K2: suppression bit-matrix via ballot, ROW-MAJOR (unchanged from round 4).
// ---------------------------------------------------------------------------
__global__ __launch_bounds__(256) void k_mask(const float4* __restrict__ sbox,
                                              u64* __restrict__ mask) {
    const int b = blockIdx.z;
    const int wc = blockIdx.x;
    const int wave = threadIdx.x >> 6;
    const int lane = threadIdx.x & 63;
    const int j = wc * 64 + lane;
    const int rbase = blockIdx.y * 1024 + wave * 256;
    const int rend = min(rbase + 256, wc * 64 + 64);
    if (rend <= rbase) return;

    const float4* S = sbox + b * N;
    const float4 cb = S[j];
    const float carea = (cb.z - cb.x) * (cb.w - cb.y);
    u64* M = mask + (size_t)b * N * NW;

    for (int row = rbase; row < rend; ++row) {
        float4 rb = S[row];
        float rarea = (rb.z - rb.x) * (rb.w - rb.y);
        float ix1 = fmaxf(rb.x, cb.x), iy1 = fmaxf(rb.y, cb.y);
        float ix2 = fminf(rb.z, cb.z), iy2 = fminf(rb.w, cb.w);
        float iw = fmaxf(ix2 - ix1, 0.0f), ih = fmaxf(iy2 - iy1, 0.0f);
        float inter = iw * ih;
        float iou = inter / (rarea + carea - inter + 1e-9f);  // IEEE, same as ref
        bool sup = (iou > IOU_THR) && (j > row);
        u64 word = __ballot(sup);
        if (lane == 0) M[(size_t)row * NW + wc] = word;
    }
}

// ---------------------------------------------------------------------------
// K3: 4-wave scan. Streaming skeleton = round 4. NEW resolve: per 64-block,
// wave 0 hoists the diagonal 64x64 bit-block into SGPRs via 96 INDEPENDENT
// v_readlanes (pipelined), then runs two branchless 32-step pure-SALU chains
// (s_bfe/s_cselect/s_or, ~4cyc/step) on 32-bit halves + a 32-term SALU
// accumulation carrying A-half keeps into the B-half entry. No branch and no
// readlane on the serial chain. sched_barrier(0) fences the three phases to
// cap live-SGPR count. DMA issue moved AFTER each wave's LDS reads.
// ---------------------------------------------------------------------------
__global__ __launch_bounds__(256, 1) void k_scan(const u64* __restrict__ mask,
                                                 const u64* __restrict__ svalidW,
                                                 u64* __restrict__ keptW) {
    __shared__ u64 chunk[3][4096];   // 3 x 32 KB
    __shared__ u64 part[4];
    __shared__ u64 kwLDS;
    __shared__ u64 keptLDS[64];
    const int img = blockIdx.x;
    const int w = threadIdx.x >> 6;
    const int lane = threadIdx.x & 63;
    const u64* Mi = mask + (size_t)img * N * NW;

    u64 removed = 0;
    u64 vvalid = 0;
    if (w == 0) vvalid = svalidW[img * NW + lane];

    // prime: chunks 0 and 1
#pragma unroll
    for (int c = 0; c < 8; ++c)
        __builtin_amdgcn_global_load_lds(
            (const unsigned*)((const char*)Mi + (size_t)(c * 4 + w) * 1024 + lane * 16),
            (unsigned*)((char*)&chunk[0][0] + (c * 4 + w) * 1024), 16, 0, 0);
    asm volatile("" ::: "memory");
#pragma unroll
    for (int c = 0; c < 8; ++c)
        __builtin_amdgcn_global_load_lds(
            (const unsigned*)((const char*)Mi + 32768 + (size_t)(c * 4 + w) * 1024 + lane * 16),
            (unsigned*)((char*)&chunk[1][0] + (c * 4 + w) * 1024), 16, 0, 0);
    asm volatile("" ::: "memory");

    for (int bb = 0; bb < 64; ++bb) {
        const u64* cbuf = &chunk[bb % 3][0];
        const int bs = (bb + 2 > 63) ? 63 : (bb + 2);
        const char* gsc = (const char*)Mi + (size_t)bs * 32768;
        char* dbase = (char*)&chunk[(bb + 2) % 3][0];

        // s1: contribute this wave's removed-word for block bb
        u64 rd = readlane64(removed, bb);
        if (lane == 0) part[w] = rd;
        // s2: chunk bb resident + part visible; keep bb+1 prefetch in flight
        if (bb == 0) asm volatile("s_waitcnt vmcnt(0) lgkmcnt(0)" ::: "memory");
        else         asm volatile("s_waitcnt vmcnt(8) lgkmcnt(0)" ::: "memory");
        __builtin_amdgcn_s_barrier();
        asm volatile("" ::: "memory");

        if (w == 0) {
            // --- diag block -> registers (one LDS read, off the chain)
            u64 dg = cbuf[(size_t)lane * 64 + bb];   // row 64bb+lane, word bb
            unsigned dlo = (unsigned)dg;             // cols 0..31 (rows<32 only)
            unsigned dhi = (unsigned)(dg >> 32);     // cols 32..63
            // wave 0's slice of chunk bb+2 DMA (after the ds_read above)
#pragma unroll
            for (int c = 0; c < 8; ++c)
                __builtin_amdgcn_global_load_lds(
                    (const unsigned*)(gsc + (size_t)(c * 4 + 0) * 1024 + lane * 16),
                    (unsigned*)(dbase + (c * 4 + 0) * 1024), 16, 0, 0);
            asm volatile("" ::: "memory");

            u64 ps = part[0] | part[1] | part[2] | part[3];
            u64 ent = ~readlane64(vvalid, bb) | readfirstlane64(ps);

            // --- phase 1: chain A (rows/bits 0..31)
            unsigned dA[32];
#pragma unroll
            for (int v = 0; v < 32; ++v)
                dA[v] = (unsigned)__builtin_amdgcn_readlane((int)dlo, v);
            unsigned curA = (unsigned)ent;
#pragma unroll
            for (int v = 0; v < 32; ++v)
                curA |= (((curA >> v) & 1u) ? 0u : dA[v]);
            unsigned kwA = ~curA;
            __builtin_amdgcn_sched_barrier(0);

            // --- phase 2: A-keeps' suppressions into B window (accumulation)
            unsigned accB = 0;
#pragma unroll
            for (int v = 0; v < 32; ++v) {
                unsigned hv = (unsigned)__builtin_amdgcn_readlane((int)dhi, v);
                accB |= (((kwA >> v) & 1u) ? hv : 0u);
            }
            __builtin_amdgcn_sched_barrier(0);

            // --- phase 3: chain B (rows/bits 32..63)
            unsigned dB[32];
#pragma unroll
            for (int v = 0; v < 32; ++v)
                dB[v] = (unsigned)__builtin_amdgcn_readlane((int)dhi, 32 + v);
            unsigned curB = (unsigned)(ent >> 32) | accB;
#pragma unroll
            for (int v = 0; v < 32; ++v)
                curB |= (((curB >> v) & 1u) ? 0u : dB[v]);

            u64 kw = ((u64)(~curB) << 32) | (u64)kwA;
            if (lane == 0) { kwLDS = kw; keptLDS[bb] = kw; }
        }
        // s4: broadcast kw (no vmcnt drain -> prefetch stays in flight)
        asm volatile("s_waitcnt lgkmcnt(0)" ::: "memory");
        __builtin_amdgcn_s_barrier();
        asm volatile("" ::: "memory");
        // s5: waves 1..3 apply kept rows, then issue their DMA slice
        if (w > 0) {
            u64 kws = readfirstlane64(kwLDS);
#pragma unroll
            for (int i = 0; i < 22; ++i) {
                int v = i * 3 + (w - 1);
                if (v < 64 && ((kws >> v) & 1ull))
                    removed |= cbuf[(size_t)v * 64 + lane];
            }
            asm volatile("" ::: "memory");
#pragma unroll
            for (int c = 0; c < 8; ++c)
                __builtin_amdgcn_global_load_lds(
                    (const unsigned*)(gsc + (size_t)(c * 4 + w) * 1024 + lane * 16),
                    (unsigned*)(dbase + (c * 4 + w) * 1024), 16, 0, 0);
            asm volatile("" ::: "memory");
        }
    }
    if (w == 0) keptW[img * NW + lane] = keptLDS[lane];
}

// ---------------------------------------------------------------------------
// K4: scatter output (unchanged).
// ---------------------------------------------------------------------------
__global__ __launch_bounds__(256) void k_out(const float* __restrict__ preds,
                                             const int* __restrict__ sidx,
                                             const u64* __restrict__ keptW,
                                             float* __restrict__ out) {
    const int b = blockIdx.y;
    const int p = blockIdx.x * 256 + threadIdx.x;
    const int idx = sidx[b * N + p];
    const bool keep = (keptW[b * NW + (p >> 6)] >> (p & 63)) & 1ull;
    const float* R = preds + ((size_t)b * N + idx) * 6;
    float* O = out + ((size_t)b * N + idx) * 6;
#pragma unroll
    for (int q = 0; q < 6; ++q) O[q] = keep ? R[q] : 0.0f;
}

extern "C" void kernel_launch(void* const* d_in, const int* in_sizes, int n_in,
                              void* d_out, int out_size, void* d_ws, size_t ws_size,
                              hipStream_t stream) {
    const float* preds = (const float*)d_in[0];
    float* out = (float*)d_out;

    u64* mask = (u64*)d_ws;
    char* p = (char*)d_ws + (size_t)BS * N * NW * sizeof(u64);
    float4* sbox = (float4*)p;      p += (size_t)BS * N * sizeof(float4);
    int* sidx = (int*)p;            p += (size_t)BS * N * sizeof(int);
    u64* svalidW = (u64*)p;         p += (size_t)BS * NW * sizeof(u64);
    u64* keptW = (u64*)p;

    k_sort<<<BS, 1024, 0, stream>>>(preds, sbox, sidx, svalidW);
    k_mask<<<dim3(NW, 4, BS), 256, 0, stream>>>(sbox, mask);
    k_scan<<<BS, 256, 0, stream>>>(mask, svalidW, keptW);
    k_out<<<dim3(N / 256, BS), 256, 0, stream>>>(preds, sidx, keptW, out);
}